// Round 1
// baseline (1907.344 us; speedup 1.0000x reference)
//
#include <hip/hip_runtime.h>
#include <hip/hip_bf16.h>

// Problem constants (fixed by the reference)
#define BDIM 2
#define SEQ  2048
#define HID  1024
#define NH   16
#define HD   64
#define MROWS (BDIM * SEQ)   // 4096
#define QKVN  (3 * HID)      // 3072

// ---------------------------------------------------------------------------
// GEMM: C[m][n] = sum_k A[m][k] * W[n][k] + bias[n]
// A: [M,K] row-major, W: [N,K] row-major (torch Linear weight layout).
// 128x128 tile, BK=8, 256 threads, 8x8 per-thread micro-tile in 4 quadrants.
// ---------------------------------------------------------------------------
__global__ __launch_bounds__(256) void gemm_nt_bias(
    const float* __restrict__ A, const float* __restrict__ W,
    const float* __restrict__ bias, float* __restrict__ C,
    int M, int N, int K)
{
    const int t  = threadIdx.x;
    const int tx = t & 15;       // 0..15 -> column groups
    const int ty = t >> 4;       // 0..15 -> row groups
    const int bm = blockIdx.y * 128;
    const int bn = blockIdx.x * 128;

    __shared__ float As[8][132];  // [k][m], pad 132 keeps stores ~2-way
    __shared__ float Ws[8][132];  // [k][n]

    float acc[8][8];
#pragma unroll
    for (int i = 0; i < 8; ++i)
#pragma unroll
        for (int j = 0; j < 8; ++j) acc[i][j] = 0.f;

    const int lr = t >> 1;          // 0..127: tile row loaded by this thread
    const int lk = (t & 1) << 2;    // 0 or 4: k sub-offset (float4)
    const float* Ag = A + (size_t)(bm + lr) * K + lk;
    const float* Wg = W + (size_t)(bn + lr) * K + lk;

    for (int k0 = 0; k0 < K; k0 += 8) {
        float4 av = *(const float4*)(Ag + k0);
        float4 wv = *(const float4*)(Wg + k0);
        __syncthreads();   // previous iteration's reads done
        As[lk + 0][lr] = av.x; As[lk + 1][lr] = av.y;
        As[lk + 2][lr] = av.z; As[lk + 3][lr] = av.w;
        Ws[lk + 0][lr] = wv.x; Ws[lk + 1][lr] = wv.y;
        Ws[lk + 2][lr] = wv.z; Ws[lk + 3][lr] = wv.w;
        __syncthreads();
#pragma unroll
        for (int kk = 0; kk < 8; ++kk) {
            float a[8], b[8];
            *(float4*)&a[0] = *(const float4*)&As[kk][ty * 4];
            *(float4*)&a[4] = *(const float4*)&As[kk][64 + ty * 4];
            *(float4*)&b[0] = *(const float4*)&Ws[kk][tx * 4];
            *(float4*)&b[4] = *(const float4*)&Ws[kk][64 + tx * 4];
#pragma unroll
            for (int i = 0; i < 8; ++i)
#pragma unroll
                for (int j = 0; j < 8; ++j)
                    acc[i][j] += a[i] * b[j];
        }
    }

#pragma unroll
    for (int ih = 0; ih < 2; ++ih) {
#pragma unroll
        for (int i = 0; i < 4; ++i) {
            const int r = bm + ih * 64 + ty * 4 + i;
#pragma unroll
            for (int jh = 0; jh < 2; ++jh) {
                const int cb = bn + jh * 64 + tx * 4;
                float4 v;
                v.x = acc[ih * 4 + i][jh * 4 + 0] + bias[cb + 0];
                v.y = acc[ih * 4 + i][jh * 4 + 1] + bias[cb + 1];
                v.z = acc[ih * 4 + i][jh * 4 + 2] + bias[cb + 2];
                v.w = acc[ih * 4 + i][jh * 4 + 3] + bias[cb + 3];
                *(float4*)(C + (size_t)r * N + cb) = v;
            }
        }
    }
}

// ---------------------------------------------------------------------------
// Flash attention, fp32. One block = one (b, h, 64-q-row tile).
// 256 threads: thread t owns q-row r=t/4 and head-dim slice d0=(t&3)*16.
// LDS [64][64] tiles with float4-granularity XOR swizzle (c4 ^ (row&15)) --
// without it the Q/P row-broadcast reads are 16-way bank conflicts
// (row stride 64 floats == 0 mod 32 banks).
// ---------------------------------------------------------------------------
__global__ __launch_bounds__(256) void attn_fwd(
    const float* __restrict__ qkv, float* __restrict__ attn_out)
{
    const int bh = blockIdx.y;          // b*NH + h
    const int b  = bh >> 4;
    const int h  = bh & 15;
    const int q0 = blockIdx.x * 64;
    const int t  = threadIdx.x;

    __shared__ float Qs[64][64];
    __shared__ float Ks[64][64];
    __shared__ float Vs[64][64];
    __shared__ float Ps[64][64];

    const float* base = qkv + (size_t)b * SEQ * QKVN + (size_t)h * (3 * HD);

    // Load Q tile (pre-scaled by 1/sqrt(64) = 0.125)
    for (int idx = t; idx < 64 * 16; idx += 256) {
        const int rr = idx >> 4;
        const int c4 = idx & 15;
        float4 v = *(const float4*)(base + (size_t)(q0 + rr) * QKVN + (c4 << 2));
        float* dst = &Qs[rr][(c4 ^ (rr & 15)) << 2];
        dst[0] = v.x * 0.125f; dst[1] = v.y * 0.125f;
        dst[2] = v.z * 0.125f; dst[3] = v.w * 0.125f;
    }

    const int r  = t >> 2;    // q row 0..63
    const int g  = t & 3;     // lane group within row
    const int d0 = g << 4;    // 16-dim output slice

    float m_run = -1e30f;
    float l_run = 0.f;
    float o[16];
#pragma unroll
    for (int i = 0; i < 16; ++i) o[i] = 0.f;

    for (int kt = 0; kt < SEQ; kt += 64) {
        __syncthreads();   // prior iteration's P/V reads done; Q visible (1st iter)
        for (int idx = t; idx < 64 * 16; idx += 256) {
            const int rr = idx >> 4;
            const int c4 = idx & 15;
            const float* src = base + (size_t)(kt + rr) * QKVN;
            float4 kv = *(const float4*)(src + HD + (c4 << 2));
            float4 vv = *(const float4*)(src + 2 * HD + (c4 << 2));
            *(float4*)&Ks[rr][(c4 ^ (rr & 15)) << 2] = kv;
            *(float4*)&Vs[rr][(c4 ^ (rr & 15)) << 2] = vv;
        }
        __syncthreads();

        // Scores for 16 k-columns kc = g + 4*j (strided so the 4 lanes of a
        // row cover all 64 columns)
        float sc[16];
#pragma unroll
        for (int j = 0; j < 16; ++j) sc[j] = 0.f;
#pragma unroll
        for (int c4 = 0; c4 < 16; ++c4) {
            float4 qv = *(const float4*)&Qs[r][(c4 ^ (r & 15)) << 2];
#pragma unroll
            for (int j = 0; j < 16; ++j) {
                const int kc = g + (j << 2);
                float4 kv = *(const float4*)&Ks[kc][(c4 ^ (kc & 15)) << 2];
                sc[j] += qv.x * kv.x + qv.y * kv.y + qv.z * kv.z + qv.w * kv.w;
            }
        }

        // Online softmax: row tile max (reduce over this thread's 16, then
        // across the 4 lanes of the row via shfl_xor 1,2)
        float tm = sc[0];
#pragma unroll
        for (int j = 1; j < 16; ++j) tm = fmaxf(tm, sc[j]);
        tm = fmaxf(tm, __shfl_xor(tm, 1));
        tm = fmaxf(tm, __shfl_xor(tm, 2));

        const float m_new = fmaxf(m_run, tm);
        const float corr  = __expf(m_run - m_new);
        float psum = 0.f;
#pragma unroll
        for (int j = 0; j < 16; ++j) {
            const float p = __expf(sc[j] - m_new);
            const int  kc = g + (j << 2);           // kc>>2 == j, kc&3 == g
            Ps[r][((j ^ (r & 15)) << 2) | g] = p;
            psum += p;
            (void)kc;
        }
        psum += __shfl_xor(psum, 1);
        psum += __shfl_xor(psum, 2);
        l_run = l_run * corr + psum;
        m_run = m_new;

#pragma unroll
        for (int i = 0; i < 16; ++i) o[i] *= corr;

        __syncthreads();   // P tile complete before PV

        // O[r][d0..d0+16] += P[r][:] @ V[:][d0..d0+16]
#pragma unroll 8
        for (int k = 0; k < 64; ++k) {
            const float pk = Ps[r][(((k >> 2) ^ (r & 15)) << 2) | (k & 3)];
#pragma unroll
            for (int u = 0; u < 4; ++u) {
                const int c4 = (d0 >> 2) + u;
                float4 vv = *(const float4*)&Vs[k][(c4 ^ (k & 15)) << 2];
                o[u * 4 + 0] += pk * vv.x;
                o[u * 4 + 1] += pk * vv.y;
                o[u * 4 + 2] += pk * vv.z;
                o[u * 4 + 3] += pk * vv.w;
            }
        }
    }

    // Normalize and write [B,S,H*HD] row-major
    const float inv = 1.f / l_run;
    float* dst = attn_out + (size_t)(b * SEQ + q0 + r) * HID + h * HD + d0;
#pragma unroll
    for (int u = 0; u < 4; ++u) {
        float4 v;
        v.x = o[u * 4 + 0] * inv; v.y = o[u * 4 + 1] * inv;
        v.z = o[u * 4 + 2] * inv; v.w = o[u * 4 + 3] * inv;
        *(float4*)(dst + u * 4) = v;
    }
}

// ---------------------------------------------------------------------------
extern "C" void kernel_launch(void* const* d_in, const int* in_sizes, int n_in,
                              void* d_out, int out_size, void* d_ws, size_t ws_size,
                              hipStream_t stream) {
    const float* x     = (const float*)d_in[0];
    const float* qkv_w = (const float*)d_in[1];
    const float* qkv_b = (const float*)d_in[2];
    const float* o_w   = (const float*)d_in[3];
    const float* o_b   = (const float*)d_in[4];
    float* out = (float*)d_out;

    float* qkv = (float*)d_ws;                          // [4096][3072]
    float* att = qkv + (size_t)MROWS * QKVN;            // [4096][1024]

    // 1) qkv = x @ qkv_w^T + qkv_b
    gemm_nt_bias<<<dim3(QKVN / 128, MROWS / 128), 256, 0, stream>>>(
        x, qkv_w, qkv_b, qkv, MROWS, QKVN, HID);

    // 2) per-head flash attention -> att [B,S,H*HD]
    attn_fwd<<<dim3(SEQ / 64, BDIM * NH), 256, 0, stream>>>(qkv, att);

    // 3) out = att @ o_w^T + o_b
    gemm_nt_bias<<<dim3(HID / 128, MROWS / 128), 256, 0, stream>>>(
        att, o_w, o_b, out, MROWS, HID, HID);

    (void)in_sizes; (void)n_in; (void)out_size; (void)ws_size;
}

// Round 3
// 687.033 us; speedup vs baseline: 2.7762x; 2.7762x over previous
//
#include <hip/hip_runtime.h>
#include <hip/hip_bf16.h>

// Problem constants (fixed by the reference)
#define BDIM 2
#define SEQ  2048
#define HID  1024
#define NH   16
#define HD   64
#define MROWS (BDIM * SEQ)   // 4096
#define QKVN  (3 * HID)      // 3072

typedef __attribute__((ext_vector_type(8))) short s8b;   // 8 bf16 (4 VGPRs)
typedef __attribute__((ext_vector_type(4))) float f4;    // MFMA C/D

__device__ __forceinline__ unsigned f2bf(float f) {
    unsigned u = __builtin_bit_cast(unsigned, f);
    return (u + 0x7FFFu + ((u >> 16) & 1u)) >> 16;   // round-to-nearest-even
}

// XOR swizzle on 16B granules within a 128B row. (row&7)^(row>>3) spreads both
// the fragment reads (lanes 0..15 read 16 consecutive rows at one 16B column)
// and the V-transpose scatter writes (d>>3 varies across concurrent lanes).
__device__ __forceinline__ int sw_off(int row, int colbyte) {
    return row * 128 + (colbyte ^ ((((row & 7) ^ (row >> 3)) & 7) << 4));
}

// ---------------------------------------------------------------------------
// GEMM: C[m][n] = sum_k A[m][k] * W[n][k] + bias[n]   (fp32 baseline, known-good)
// ---------------------------------------------------------------------------
__global__ __launch_bounds__(256) void gemm_nt_bias(
    const float* __restrict__ A, const float* __restrict__ W,
    const float* __restrict__ bias, float* __restrict__ C,
    int M, int N, int K)
{
    const int t  = threadIdx.x;
    const int tx = t & 15;
    const int ty = t >> 4;
    const int bm = blockIdx.y * 128;
    const int bn = blockIdx.x * 128;

    __shared__ float As[8][132];
    __shared__ float Ws[8][132];

    float acc[8][8];
#pragma unroll
    for (int i = 0; i < 8; ++i)
#pragma unroll
        for (int j = 0; j < 8; ++j) acc[i][j] = 0.f;

    const int lr = t >> 1;
    const int lk = (t & 1) << 2;
    const float* Ag = A + (size_t)(bm + lr) * K + lk;
    const float* Wg = W + (size_t)(bn + lr) * K + lk;

    for (int k0 = 0; k0 < K; k0 += 8) {
        float4 av = *(const float4*)(Ag + k0);
        float4 wv = *(const float4*)(Wg + k0);
        __syncthreads();
        As[lk + 0][lr] = av.x; As[lk + 1][lr] = av.y;
        As[lk + 2][lr] = av.z; As[lk + 3][lr] = av.w;
        Ws[lk + 0][lr] = wv.x; Ws[lk + 1][lr] = wv.y;
        Ws[lk + 2][lr] = wv.z; Ws[lk + 3][lr] = wv.w;
        __syncthreads();
#pragma unroll
        for (int kk = 0; kk < 8; ++kk) {
            float a[8], b[8];
            *(float4*)&a[0] = *(const float4*)&As[kk][ty * 4];
            *(float4*)&a[4] = *(const float4*)&As[kk][64 + ty * 4];
            *(float4*)&b[0] = *(const float4*)&Ws[kk][tx * 4];
            *(float4*)&b[4] = *(const float4*)&Ws[kk][64 + tx * 4];
#pragma unroll
            for (int i = 0; i < 8; ++i)
#pragma unroll
                for (int j = 0; j < 8; ++j)
                    acc[i][j] += a[i] * b[j];
        }
    }

#pragma unroll
    for (int ih = 0; ih < 2; ++ih) {
#pragma unroll
        for (int i = 0; i < 4; ++i) {
            const int r = bm + ih * 64 + ty * 4 + i;
#pragma unroll
            for (int jh = 0; jh < 2; ++jh) {
                const int cb = bn + jh * 64 + tx * 4;
                float4 v;
                v.x = acc[ih * 4 + i][jh * 4 + 0] + bias[cb + 0];
                v.y = acc[ih * 4 + i][jh * 4 + 1] + bias[cb + 1];
                v.z = acc[ih * 4 + i][jh * 4 + 2] + bias[cb + 2];
                v.w = acc[ih * 4 + i][jh * 4 + 3] + bias[cb + 3];
                *(float4*)(C + (size_t)r * N + cb) = v;
            }
        }
    }
}

// ---------------------------------------------------------------------------
// Flash attention with bf16 MFMA. One block = (b, h, 64 q-rows); 4 waves,
// wave w owns q-rows [w*16, w*16+16). 64-key tiles.
// QKV row layout is PER-HEAD INTERLEAVED: head h occupies columns
// [h*3*HD, (h+1)*3*HD) as [Q(64) | K(64) | V(64)].  (Round-2 bug was here.)
//   QK^T: A = Q (regs, pre-scaled), B = K (LDS [key][d], swizzled)
//   PV:   A = P (wave-private LDS rows, bf16), B = V^T (LDS [d][key], swizzled)
// mfma_f32_16x16x32_bf16 D layout: col=lane&15, row=(lane>>4)*4+reg (m89).
// ---------------------------------------------------------------------------
__global__ __launch_bounds__(256) void attn_fwd_mfma(
    const float* __restrict__ qkv, float* __restrict__ attn_out)
{
    const int t   = threadIdx.x;
    const int w   = t >> 6;
    const int l   = t & 63;
    const int l15 = l & 15;
    const int lg  = l >> 4;

    const int bh = blockIdx.y;
    const int b  = bh >> 4;
    const int h  = bh & 15;
    const int q0 = blockIdx.x * 64;

    __shared__ unsigned short Ks[64 * 64];  // [key][d], swizzled
    __shared__ unsigned short Vt[64 * 64];  // [d][key], swizzled
    __shared__ unsigned short Ps[64 * 64];  // [q][key], swizzled, wave-private rows

    const float* base = qkv + (size_t)b * SEQ * QKVN + h * (3 * HD);

    // Q fragments in registers, pre-scaled by 1/sqrt(64)=0.125.
    s8b qf[2];
    {
        const float* qrow = base + (size_t)(q0 + w * 16 + l15) * QKVN;
#pragma unroll
        for (int kc = 0; kc < 2; ++kc) {
            const int d = kc * 32 + lg * 8;
            float4 a = *(const float4*)(qrow + d);
            float4 c = *(const float4*)(qrow + d + 4);
            qf[kc][0] = (short)f2bf(a.x * 0.125f);
            qf[kc][1] = (short)f2bf(a.y * 0.125f);
            qf[kc][2] = (short)f2bf(a.z * 0.125f);
            qf[kc][3] = (short)f2bf(a.w * 0.125f);
            qf[kc][4] = (short)f2bf(c.x * 0.125f);
            qf[kc][5] = (short)f2bf(c.y * 0.125f);
            qf[kc][6] = (short)f2bf(c.z * 0.125f);
            qf[kc][7] = (short)f2bf(c.w * 0.125f);
        }
    }

    float m_run[4], l_run[4];
    f4 oacc[4];
#pragma unroll
    for (int i = 0; i < 4; ++i) {
        m_run[i] = -1e30f;
        l_run[i] = 0.f;
        oacc[i]  = (f4){0.f, 0.f, 0.f, 0.f};
    }

    for (int kt = 0; kt < SEQ; kt += 64) {
        __syncthreads();   // previous tile's K/V reads complete

        // ---- stage K (16B granules) and V (transposed scatter) ----
#pragma unroll
        for (int rep = 0; rep < 2; ++rep) {
            const int idx = t + rep * 256;
            const int row = idx >> 3;   // key position within tile
            const int g   = idx & 7;    // 8-dim granule
            const float* src = base + (size_t)(kt + row) * QKVN + HD + g * 8;
            float4 k0 = *(const float4*)src;
            float4 k1 = *(const float4*)(src + 4);
            uint4 kg;
            kg.x = f2bf(k0.x) | (f2bf(k0.y) << 16);
            kg.y = f2bf(k0.z) | (f2bf(k0.w) << 16);
            kg.z = f2bf(k1.x) | (f2bf(k1.y) << 16);
            kg.w = f2bf(k1.z) | (f2bf(k1.w) << 16);
            *(uint4*)((char*)Ks + sw_off(row, g * 16)) = kg;

            const float* vsrc = src + HD;   // V block of this head
            float4 v0 = *(const float4*)vsrc;
            float4 v1 = *(const float4*)(vsrc + 4);
            const float vv[8] = {v0.x, v0.y, v0.z, v0.w, v1.x, v1.y, v1.z, v1.w};
#pragma unroll
            for (int j = 0; j < 8; ++j) {
                const int d = g * 8 + j;
                *(unsigned short*)((char*)Vt + sw_off(d, row * 2)) =
                    (unsigned short)f2bf(vv[j]);
            }
        }
        __syncthreads();   // staging visible to all waves

        // ---- QK^T: S[16 q][64 key] per wave ----
        f4 sacc[4];
#pragma unroll
        for (int nt = 0; nt < 4; ++nt) sacc[nt] = (f4){0.f, 0.f, 0.f, 0.f};
#pragma unroll
        for (int kc = 0; kc < 2; ++kc) {
            const int colb = kc * 64 + lg * 16;
#pragma unroll
            for (int nt = 0; nt < 4; ++nt) {
                s8b kf = *(const s8b*)((const char*)Ks + sw_off(nt * 16 + l15, colb));
                sacc[nt] = __builtin_amdgcn_mfma_f32_16x16x32_bf16(qf[kc], kf, sacc[nt], 0, 0, 0);
            }
        }

        // ---- online softmax (rows = lg*4+i, cols spread over lanes 0..15) ----
        float mt[4];
#pragma unroll
        for (int i = 0; i < 4; ++i)
            mt[i] = fmaxf(fmaxf(sacc[0][i], sacc[1][i]), fmaxf(sacc[2][i], sacc[3][i]));
#pragma unroll
        for (int s = 1; s <= 8; s <<= 1)
#pragma unroll
            for (int i = 0; i < 4; ++i)
                mt[i] = fmaxf(mt[i], __shfl_xor(mt[i], s));

        float corr[4], rs[4];
#pragma unroll
        for (int i = 0; i < 4; ++i) {
            const float mn = fmaxf(m_run[i], mt[i]);
            corr[i]  = __expf(m_run[i] - mn);
            m_run[i] = mn;
            rs[i]    = 0.f;
        }

        const int rowbase = w * 16 + lg * 4;
#pragma unroll
        for (int nt = 0; nt < 4; ++nt) {
#pragma unroll
            for (int i = 0; i < 4; ++i) {
                const float p = __expf(sacc[nt][i] - m_run[i]);
                rs[i] += p;
                *(unsigned short*)((char*)Ps + sw_off(rowbase + i, (nt * 16 + l15) * 2)) =
                    (unsigned short)f2bf(p);
            }
        }
#pragma unroll
        for (int s = 1; s <= 8; s <<= 1)
#pragma unroll
            for (int i = 0; i < 4; ++i)
                rs[i] += __shfl_xor(rs[i], s);
#pragma unroll
        for (int i = 0; i < 4; ++i)
            l_run[i] = l_run[i] * corr[i] + rs[i];
#pragma unroll
        for (int nt = 0; nt < 4; ++nt)
#pragma unroll
            for (int i = 0; i < 4; ++i)
                oacc[nt][i] *= corr[i];

        // ---- PV: O[16 q][64 d] += P @ V  (P reads are same-wave rows) ----
#pragma unroll
        for (int kk = 0; kk < 2; ++kk) {
            const int colb = kk * 64 + lg * 16;
            s8b pf = *(const s8b*)((const char*)Ps + sw_off(w * 16 + l15, colb));
#pragma unroll
            for (int nt = 0; nt < 4; ++nt) {
                s8b vf = *(const s8b*)((const char*)Vt + sw_off(nt * 16 + l15, colb));
                oacc[nt] = __builtin_amdgcn_mfma_f32_16x16x32_bf16(pf, vf, oacc[nt], 0, 0, 0);
            }
        }
    }

    // ---- epilogue: normalize, write [B,S,H*HD] ----
    float inv[4];
#pragma unroll
    for (int i = 0; i < 4; ++i) inv[i] = 1.f / l_run[i];
    float* obase = attn_out + (size_t)(b * SEQ + q0 + w * 16 + lg * 4) * HID + h * HD + l15;
#pragma unroll
    for (int i = 0; i < 4; ++i)
#pragma unroll
        for (int nt = 0; nt < 4; ++nt)
            obase[(size_t)i * HID + nt * 16] = oacc[nt][i] * inv[i];
}

// ---------------------------------------------------------------------------
extern "C" void kernel_launch(void* const* d_in, const int* in_sizes, int n_in,
                              void* d_out, int out_size, void* d_ws, size_t ws_size,
                              hipStream_t stream) {
    const float* x     = (const float*)d_in[0];
    const float* qkv_w = (const float*)d_in[1];
    const float* qkv_b = (const float*)d_in[2];
    const float* o_w   = (const float*)d_in[3];
    const float* o_b   = (const float*)d_in[4];
    float* out = (float*)d_out;

    float* qkv = (float*)d_ws;                          // [4096][3072]
    float* att = qkv + (size_t)MROWS * QKVN;            // [4096][1024]

    gemm_nt_bias<<<dim3(QKVN / 128, MROWS / 128), 256, 0, stream>>>(
        x, qkv_w, qkv_b, qkv, MROWS, QKVN, HID);

    attn_fwd_mfma<<<dim3(SEQ / 64, BDIM * NH), 256, 0, stream>>>(qkv, att);

    gemm_nt_bias<<<dim3(HID / 128, MROWS / 128), 256, 0, stream>>>(
        att, o_w, o_b, out, MROWS, HID, HID);

    (void)in_sizes; (void)n_in; (void)out_size; (void)ws_size;
}

// Round 4
// 570.767 us; speedup vs baseline: 3.3417x; 1.2037x over previous
//
#include <hip/hip_runtime.h>
#include <hip/hip_bf16.h>

// Problem constants (fixed by the reference)
#define BDIM 2
#define SEQ  2048
#define HID  1024
#define NH   16
#define HD   64
#define MROWS (BDIM * SEQ)   // 4096
#define QKVN  (3 * HID)      // 3072

typedef __attribute__((ext_vector_type(8))) short s8b;   // 8 bf16 (4 VGPRs)
typedef __attribute__((ext_vector_type(4))) float f4;    // MFMA C/D

__device__ __forceinline__ unsigned f2bf(float f) {
    unsigned u = __builtin_bit_cast(unsigned, f);
    return (u + 0x7FFFu + ((u >> 16) & 1u)) >> 16;   // round-to-nearest-even
}
__device__ __forceinline__ float bf2f(unsigned h) {
    return __builtin_bit_cast(float, h << 16);
}

// ---------------------------------------------------------------------------
// Prologue: split fp32 tensor into hi/lo bf16 planes. hi = bf16(x) RNE,
// lo = bf16(x - hi)  (x - hi is exact in fp32). 8 elems / thread.
// ---------------------------------------------------------------------------
__global__ __launch_bounds__(256) void split_hi_lo(
    const float* __restrict__ src, unsigned short* __restrict__ hi,
    unsigned short* __restrict__ lo, int n8)
{
    const int i = blockIdx.x * 256 + threadIdx.x;
    if (i >= n8) return;
    const float4* s = (const float4*)src + 2 * (size_t)i;
    float4 a = s[0], b = s[1];
    const float v[8] = {a.x, a.y, a.z, a.w, b.x, b.y, b.z, b.w};
    unsigned hu[8], lu[8];
#pragma unroll
    for (int j = 0; j < 8; ++j) {
        hu[j] = f2bf(v[j]);
        lu[j] = f2bf(v[j] - bf2f(hu[j]));
    }
    uint4 hv = {hu[0] | (hu[1] << 16), hu[2] | (hu[3] << 16),
                hu[4] | (hu[5] << 16), hu[6] | (hu[7] << 16)};
    uint4 lv = {lu[0] | (lu[1] << 16), lu[2] | (lu[3] << 16),
                lu[4] | (lu[5] << 16), lu[6] | (lu[7] << 16)};
    *((uint4*)hi + i) = hv;
    *((uint4*)lo + i) = lv;
}

// ---------------------------------------------------------------------------
// Split-bf16 MFMA GEMM: C[m][n] = sum_k A[m][k]*W[n][k] + bias[n], where
// A ~ Ah+Al, W ~ Wh+Wl (bf16 planes). 3 MFMA passes (hh, hl, lh); lo*lo
// dropped (~1e-5 rel). 128x128 tile, BK=32, 4 waves as 2x2 of 64x64.
// LDS rows padded to 80 B: 16B-aligned stride; start banks 20r%32 tile all
// 32 banks -> ds_read_b128 at the inherent 8-access floor (conflict-free).
// OUTBF=1 -> bf16 output (QKV path), else fp32.
// ---------------------------------------------------------------------------
template <int OUTBF>
__global__ __launch_bounds__(256) void gemm_split(
    const unsigned short* __restrict__ Ah, const unsigned short* __restrict__ Al,
    const unsigned short* __restrict__ Wh, const unsigned short* __restrict__ Wl,
    const float* __restrict__ bias, void* __restrict__ Cout, int N, int K)
{
    const int t   = threadIdx.x;
    const int l15 = t & 15;
    const int lg  = (t >> 4) & 3;
    const int w   = t >> 6;
    const int wr  = w >> 1, wc = w & 1;
    const int bm  = blockIdx.y * 128, bn = blockIdx.x * 128;

    __shared__ unsigned short AhS[128 * 40];
    __shared__ unsigned short AlS[128 * 40];
    __shared__ unsigned short WhS[128 * 40];
    __shared__ unsigned short WlS[128 * 40];

    f4 acc[4][4];
#pragma unroll
    for (int i = 0; i < 4; ++i)
#pragma unroll
        for (int j = 0; j < 4; ++j) acc[i][j] = (f4){0.f, 0.f, 0.f, 0.f};

    // staging map: thread t loads granule (row=t>>2, col8=(t&3)*8) and the
    // same at row+64, for each of the 4 planes (16 B each).
    const int sr = t >> 2;
    const int sc = (t & 3) * 8;
    const size_t aoff0 = (size_t)(bm + sr) * K + sc;
    const size_t aoff1 = (size_t)(bm + 64 + sr) * K + sc;
    const size_t woff0 = (size_t)(bn + sr) * K + sc;
    const size_t woff1 = (size_t)(bn + 64 + sr) * K + sc;
    const int dsb0 = sr * 80 + sc * 2;
    const int dsb1 = (64 + sr) * 80 + sc * 2;

    uint4 g[8];
#define LOADK(k0)                                                     \
    do {                                                              \
        g[0] = *(const uint4*)(Ah + aoff0 + (k0));                    \
        g[1] = *(const uint4*)(Ah + aoff1 + (k0));                    \
        g[2] = *(const uint4*)(Al + aoff0 + (k0));                    \
        g[3] = *(const uint4*)(Al + aoff1 + (k0));                    \
        g[4] = *(const uint4*)(Wh + woff0 + (k0));                    \
        g[5] = *(const uint4*)(Wh + woff1 + (k0));                    \
        g[6] = *(const uint4*)(Wl + woff0 + (k0));                    \
        g[7] = *(const uint4*)(Wl + woff1 + (k0));                    \
    } while (0)

    LOADK(0);
    for (int k0 = 0; k0 < K; k0 += 32) {
        __syncthreads();   // previous iteration's fragment reads done
        *(uint4*)((char*)AhS + dsb0) = g[0];
        *(uint4*)((char*)AhS + dsb1) = g[1];
        *(uint4*)((char*)AlS + dsb0) = g[2];
        *(uint4*)((char*)AlS + dsb1) = g[3];
        *(uint4*)((char*)WhS + dsb0) = g[4];
        *(uint4*)((char*)WhS + dsb1) = g[5];
        *(uint4*)((char*)WlS + dsb0) = g[6];
        *(uint4*)((char*)WlS + dsb1) = g[7];
        __syncthreads();
        if (k0 + 32 < K) LOADK(k0 + 32);   // issue early; MFMA phase hides HBM

        s8b bh[4], bl[4];
#pragma unroll
        for (int nt = 0; nt < 4; ++nt) {
            const int rb = (wc * 64 + nt * 16 + l15) * 80 + lg * 16;
            bh[nt] = *(const s8b*)((const char*)WhS + rb);
            bl[nt] = *(const s8b*)((const char*)WlS + rb);
        }
#pragma unroll
        for (int mt = 0; mt < 4; ++mt) {
            const int rb = (wr * 64 + mt * 16 + l15) * 80 + lg * 16;
            s8b ah = *(const s8b*)((const char*)AhS + rb);
            s8b al = *(const s8b*)((const char*)AlS + rb);
#pragma unroll
            for (int nt = 0; nt < 4; ++nt) {
                acc[mt][nt] = __builtin_amdgcn_mfma_f32_16x16x32_bf16(ah, bh[nt], acc[mt][nt], 0, 0, 0);
                acc[mt][nt] = __builtin_amdgcn_mfma_f32_16x16x32_bf16(ah, bl[nt], acc[mt][nt], 0, 0, 0);
                acc[mt][nt] = __builtin_amdgcn_mfma_f32_16x16x32_bf16(al, bh[nt], acc[mt][nt], 0, 0, 0);
            }
        }
    }
#undef LOADK

    float bv[4];
#pragma unroll
    for (int nt = 0; nt < 4; ++nt) bv[nt] = bias[bn + wc * 64 + nt * 16 + l15];

#pragma unroll
    for (int mt = 0; mt < 4; ++mt)
#pragma unroll
        for (int i = 0; i < 4; ++i) {
            const int m = bm + wr * 64 + mt * 16 + lg * 4 + i;
#pragma unroll
            for (int nt = 0; nt < 4; ++nt) {
                const int n = bn + wc * 64 + nt * 16 + l15;
                const float v = acc[mt][nt][i] + bv[nt];
                if (OUTBF)
                    ((unsigned short*)Cout)[(size_t)m * N + n] = (unsigned short)f2bf(v);
                else
                    ((float*)Cout)[(size_t)m * N + n] = v;
            }
        }
}

// ---------------------------------------------------------------------------
// XOR swizzle on 16B granules within a 128B row (attention LDS tiles).
// ---------------------------------------------------------------------------
__device__ __forceinline__ int sw_off(int row, int colbyte) {
    return row * 128 + (colbyte ^ ((((row & 7) ^ (row >> 3)) & 7) << 4));
}

// ---------------------------------------------------------------------------
// Flash attention, bf16-MFMA, bf16 qkv input ([B,S,3072], per-head
// interleaved: head h = cols [h*192, h*192+192) as Q|K|V of 64 each).
// One block = (b, h, 64 q-rows); 4 waves, wave w owns rows [w*16, w*16+16).
// 1/sqrt(64) folded into scores post-MFMA. Output: hi/lo bf16 planes for
// the split O-projection.
// ---------------------------------------------------------------------------
__global__ __launch_bounds__(256) void attn_fwd_mfma(
    const unsigned short* __restrict__ qkv,
    unsigned short* __restrict__ att_hi, unsigned short* __restrict__ att_lo)
{
    const int t   = threadIdx.x;
    const int w   = t >> 6;
    const int l   = t & 63;
    const int l15 = l & 15;
    const int lg  = l >> 4;

    const int bh = blockIdx.y;
    const int b  = bh >> 4;
    const int h  = bh & 15;
    const int q0 = blockIdx.x * 64;

    __shared__ unsigned short Ks[64 * 64];  // [key][d], swizzled
    __shared__ unsigned short Vt[64 * 64];  // [d][key], swizzled
    __shared__ unsigned short Ps[64 * 64];  // [q][key], swizzled, wave-private rows

    const unsigned short* base = qkv + (size_t)b * SEQ * QKVN + h * (3 * HD);

    // Q fragments: direct bf16 loads (no conversion, no pre-scale)
    s8b qf[2];
    {
        const unsigned short* qrow = base + (size_t)(q0 + w * 16 + l15) * QKVN;
        qf[0] = *(const s8b*)(qrow + lg * 8);
        qf[1] = *(const s8b*)(qrow + 32 + lg * 8);
    }

    float m_run[4], l_run[4];
    f4 oacc[4];
#pragma unroll
    for (int i = 0; i < 4; ++i) {
        m_run[i] = -1e30f;
        l_run[i] = 0.f;
        oacc[i]  = (f4){0.f, 0.f, 0.f, 0.f};
    }

    for (int kt = 0; kt < SEQ; kt += 64) {
        __syncthreads();   // previous tile's K/V reads complete

        // ---- stage K (16B copies) and V (transposed scatter), pure moves ----
#pragma unroll
        for (int rep = 0; rep < 2; ++rep) {
            const int idx = t + rep * 256;
            const int row = idx >> 3;   // key position within tile
            const int gg  = idx & 7;    // 8-elem granule
            const unsigned short* src = base + (size_t)(kt + row) * QKVN + HD + gg * 8;
            uint4 kg = *(const uint4*)src;
            *(uint4*)((char*)Ks + sw_off(row, gg * 16)) = kg;

            s8b v8 = *(const s8b*)(src + HD);
#pragma unroll
            for (int j = 0; j < 8; ++j)
                *(unsigned short*)((char*)Vt + sw_off(gg * 8 + j, row * 2)) =
                    (unsigned short)v8[j];
        }
        __syncthreads();

        // ---- QK^T: S[16 q][64 key] per wave ----
        f4 sacc[4];
#pragma unroll
        for (int nt = 0; nt < 4; ++nt) sacc[nt] = (f4){0.f, 0.f, 0.f, 0.f};
#pragma unroll
        for (int kc = 0; kc < 2; ++kc) {
            const int colb = kc * 64 + lg * 16;
#pragma unroll
            for (int nt = 0; nt < 4; ++nt) {
                s8b kf = *(const s8b*)((const char*)Ks + sw_off(nt * 16 + l15, colb));
                sacc[nt] = __builtin_amdgcn_mfma_f32_16x16x32_bf16(qf[kc], kf, sacc[nt], 0, 0, 0);
            }
        }
        // fold 1/sqrt(HD)
#pragma unroll
        for (int nt = 0; nt < 4; ++nt)
#pragma unroll
            for (int i = 0; i < 4; ++i) sacc[nt][i] *= 0.125f;

        // ---- online softmax ----
        float mt4[4];
#pragma unroll
        for (int i = 0; i < 4; ++i)
            mt4[i] = fmaxf(fmaxf(sacc[0][i], sacc[1][i]), fmaxf(sacc[2][i], sacc[3][i]));
#pragma unroll
        for (int s = 1; s <= 8; s <<= 1)
#pragma unroll
            for (int i = 0; i < 4; ++i)
                mt4[i] = fmaxf(mt4[i], __shfl_xor(mt4[i], s));

        float corr[4], rs[4];
#pragma unroll
        for (int i = 0; i < 4; ++i) {
            const float mn = fmaxf(m_run[i], mt4[i]);
            corr[i]  = __expf(m_run[i] - mn);
            m_run[i] = mn;
            rs[i]    = 0.f;
        }

        const int rowbase = w * 16 + lg * 4;
#pragma unroll
        for (int nt = 0; nt < 4; ++nt) {
#pragma unroll
            for (int i = 0; i < 4; ++i) {
                const float p = __expf(sacc[nt][i] - m_run[i]);
                rs[i] += p;
                *(unsigned short*)((char*)Ps + sw_off(rowbase + i, (nt * 16 + l15) * 2)) =
                    (unsigned short)f2bf(p);
            }
        }
#pragma unroll
        for (int s = 1; s <= 8; s <<= 1)
#pragma unroll
            for (int i = 0; i < 4; ++i)
                rs[i] += __shfl_xor(rs[i], s);
#pragma unroll
        for (int i = 0; i < 4; ++i)
            l_run[i] = l_run[i] * corr[i] + rs[i];
#pragma unroll
        for (int nt = 0; nt < 4; ++nt)
#pragma unroll
            for (int i = 0; i < 4; ++i)
                oacc[nt][i] *= corr[i];

        // ---- PV: O[16 q][64 d] += P @ V ----
#pragma unroll
        for (int kk = 0; kk < 2; ++kk) {
            const int colb = kk * 64 + lg * 16;
            s8b pf = *(const s8b*)((const char*)Ps + sw_off(w * 16 + l15, colb));
#pragma unroll
            for (int nt = 0; nt < 4; ++nt) {
                s8b vf = *(const s8b*)((const char*)Vt + sw_off(nt * 16 + l15, colb));
                oacc[nt] = __builtin_amdgcn_mfma_f32_16x16x32_bf16(pf, vf, oacc[nt], 0, 0, 0);
            }
        }
    }

    // ---- epilogue: normalize, split into hi/lo bf16 planes [B,S,HID] ----
    float inv[4];
#pragma unroll
    for (int i = 0; i < 4; ++i) inv[i] = 1.f / l_run[i];
#pragma unroll
    for (int i = 0; i < 4; ++i) {
        const size_t rowb = (size_t)(b * SEQ + q0 + w * 16 + lg * 4 + i) * HID + h * HD + l15;
#pragma unroll
        for (int nt = 0; nt < 4; ++nt) {
            const float v = oacc[nt][i] * inv[i];
            const unsigned hu = f2bf(v);
            const unsigned lu = f2bf(v - bf2f(hu));
            att_hi[rowb + nt * 16] = (unsigned short)hu;
            att_lo[rowb + nt * 16] = (unsigned short)lu;
        }
    }
}

// ---------------------------------------------------------------------------
// Workspace layout (56 MB total; harness ws proven >= 64 MB):
//   qkv_bf [4096][3072] bf16              24 MB
//   wh, wl [3072][1024] bf16          2 x  6 MB
//   owh, owl [1024][1024] bf16        2 x  2 MB
//   xh, xl [4096][1024] bf16          2 x  8 MB   (aliased by att_hi/att_lo
//                                                  after the QKV GEMM is done)
// ---------------------------------------------------------------------------
extern "C" void kernel_launch(void* const* d_in, const int* in_sizes, int n_in,
                              void* d_out, int out_size, void* d_ws, size_t ws_size,
                              hipStream_t stream) {
    const float* x     = (const float*)d_in[0];
    const float* qkv_w = (const float*)d_in[1];
    const float* qkv_b = (const float*)d_in[2];
    const float* o_w   = (const float*)d_in[3];
    const float* o_b   = (const float*)d_in[4];
    float* out = (float*)d_out;

    char* ws = (char*)d_ws;
    unsigned short* qkv_bf = (unsigned short*)ws;                      ws += (size_t)MROWS * QKVN * 2;
    unsigned short* wh     = (unsigned short*)ws;                      ws += (size_t)QKVN * HID * 2;
    unsigned short* wl     = (unsigned short*)ws;                      ws += (size_t)QKVN * HID * 2;
    unsigned short* owh    = (unsigned short*)ws;                      ws += (size_t)HID * HID * 2;
    unsigned short* owl    = (unsigned short*)ws;                      ws += (size_t)HID * HID * 2;
    unsigned short* xh     = (unsigned short*)ws;                      ws += (size_t)MROWS * HID * 2;
    unsigned short* xl     = (unsigned short*)ws;
    unsigned short* att_hi = xh;   // alias: x planes dead after QKV GEMM
    unsigned short* att_lo = xl;

    split_hi_lo<<<(MROWS * HID / 8) / 256, 256, 0, stream>>>(x, xh, xl, MROWS * HID / 8);
    split_hi_lo<<<(QKVN * HID / 8) / 256, 256, 0, stream>>>(qkv_w, wh, wl, QKVN * HID / 8);
    split_hi_lo<<<(HID * HID / 8) / 256, 256, 0, stream>>>(o_w, owh, owl, HID * HID / 8);

    gemm_split<1><<<dim3(QKVN / 128, MROWS / 128), 256, 0, stream>>>(
        xh, xl, wh, wl, qkv_b, qkv_bf, QKVN, HID);

    attn_fwd_mfma<<<dim3(SEQ / 64, BDIM * NH), 256, 0, stream>>>(qkv_bf, att_hi, att_lo);

    gemm_split<0><<<dim3(HID / 128, MROWS / 128), 256, 0, stream>>>(
        att_hi, att_lo, owh, owl, o_b, out, HID, HID);

    (void)in_sizes; (void)n_in; (void)out_size; (void)ws_size;
}